// Round 3
// baseline (329.993 us; speedup 1.0000x reference)
//
#include <hip/hip_runtime.h>

// Requires ws_size >= 22 MiB.
// ws layout (bytes):
//   xb   @ 0        : [4096][512] bf16   (x converted)            4 MiB
//   wqt  @ 4M       : [512][512]  bf16   (Wq^T)                 0.5 MiB
//   wkt  @ 4M+512K  : Wk^T                                      0.5 MiB
//   wvt  @ 5M       : Wv^T                                      0.5 MiB
//   wpt  @ 5M+512K  : Wp^T                                      0.5 MiB
//   Qb   @ 6M       : [B*T][512] bf16                             4 MiB
//   Kb   @ 10M      : [B*T][512] bf16                             4 MiB
//   Vtb  @ 14M      : [B*H*64][2048] bf16  (V transposed)         4 MiB
//   yb   @ 18M      : [B*T][512] bf16  (attention output)         4 MiB

typedef unsigned short u16;
typedef unsigned int   u32;
typedef __bf16 bf16x8 __attribute__((ext_vector_type(8)));
typedef float  f32x4  __attribute__((ext_vector_type(4)));
typedef short  s16x4  __attribute__((ext_vector_type(4)));

static __device__ __forceinline__ u16 f2b(float f) {
  __bf16 h = (__bf16)f;
  return __builtin_bit_cast(u16, h);
}
static __device__ __forceinline__ u32 pack2(float a, float b) {
  return (u32)f2b(a) | ((u32)f2b(b) << 16);
}
static __device__ __forceinline__ bf16x8 ld_bf16x8(const u16* p) {
  uint4 u = *(const uint4*)p;
  return __builtin_bit_cast(bf16x8, u);
}
static __device__ __forceinline__ f32x4 mfma32(bf16x8 a, bf16x8 b, f32x4 c) {
  return __builtin_amdgcn_mfma_f32_16x16x32_bf16(a, b, c, 0, 0, 0);
}
static __device__ __forceinline__ f32x4 mfma16(s16x4 a, s16x4 b, f32x4 c) {
  return __builtin_amdgcn_mfma_f32_16x16x16bf16_1k(a, b, c, 0, 0, 0);
}

// ---------------- convert x: f32 -> bf16, [4096][512] ----------------
__global__ __launch_bounds__(256) void k_cvt_x(const float* __restrict__ x,
                                               u16* __restrict__ xb) {
  int i = blockIdx.x * 256 + threadIdx.x;   // each thread: 8 elements
  const float4* s = (const float4*)x;
  float4 a = s[2 * i], b = s[2 * i + 1];
  uint4 o;
  o.x = pack2(a.x, a.y);
  o.y = pack2(a.z, a.w);
  o.z = pack2(b.x, b.y);
  o.w = pack2(b.z, b.w);
  ((uint4*)xb)[i] = o;
}

// ------------- convert + transpose weights: Wt[n][k] = W[k][n] -------------
__global__ __launch_bounds__(256) void k_cvt_w(
    const float* __restrict__ Wq, const float* __restrict__ Wk,
    const float* __restrict__ Wv, const float* __restrict__ Wp,
    u16* __restrict__ oq, u16* __restrict__ ok,
    u16* __restrict__ ov, u16* __restrict__ op) {
  const int z = blockIdx.z;
  const float* src = (z == 0) ? Wq : (z == 1) ? Wk : (z == 2) ? Wv : Wp;
  u16* dst = (z == 0) ? oq : (z == 1) ? ok : (z == 2) ? ov : op;
  __shared__ float t[32][33];
  const int tx = threadIdx.x, ty = threadIdx.y;       // 32 x 8
  const int n0 = blockIdx.x * 32, k0 = blockIdx.y * 32;
#pragma unroll
  for (int i = 0; i < 4; ++i)
    t[ty + i * 8][tx] = src[(size_t)(k0 + ty + i * 8) * 512 + n0 + tx];
  __syncthreads();
#pragma unroll
  for (int i = 0; i < 4; ++i)
    dst[(size_t)(n0 + ty + i * 8) * 512 + k0 + tx] = f2b(t[tx][ty + i * 8]);
}

// ---------------- GEMM: C[m][n] = sum_k A[m][k] * Bt[n][k] + bias[n] -------
// M=4096, N=512, K=512. Tile 128x64, BK=64, 4 waves (2x2), 16x16x32 MFMA.
// mode 0: out bf16 [M][N]        (Q, K)
// mode 1: out bf16 Vt[B,H,D,T]   (V transposed)
// mode 2: out f32  [M][N]        (final projection)
__global__ __launch_bounds__(256) void k_gemm(
    const u16* __restrict__ A,
    const u16* __restrict__ Bt_0, const u16* __restrict__ Bt_1,
    const u16* __restrict__ Bt_2,
    const float* __restrict__ bias_0, const float* __restrict__ bias_1,
    const float* __restrict__ bias_2,
    void* out_0, void* out_1, void* out_2,
    int mode_0, int mode_1, int mode_2) {
  const int z = blockIdx.z;
  const u16* Bt = (z == 0) ? Bt_0 : (z == 1) ? Bt_1 : Bt_2;
  const float* bias = (z == 0) ? bias_0 : (z == 1) ? bias_1 : bias_2;
  void* outp = (z == 0) ? out_0 : (z == 1) ? out_1 : out_2;
  const int mode = (z == 0) ? mode_0 : (z == 1) ? mode_1 : mode_2;

  const int tid = threadIdx.x, lane = tid & 63, w = tid >> 6;
  const int wm = w >> 1, wn = w & 1;
  const int lr = lane & 15, lg = lane >> 4;
  const int m0 = blockIdx.y * 128, n0 = blockIdx.x * 64;

  __shared__ __align__(16) u16 As[128 * 64];
  __shared__ __align__(16) u16 Bs[64 * 64];

  f32x4 acc[4][2];
  const f32x4 fz = {0.f, 0.f, 0.f, 0.f};
#pragma unroll
  for (int mi = 0; mi < 4; ++mi)
#pragma unroll
    for (int ni = 0; ni < 2; ++ni) acc[mi][ni] = fz;

  uint4 pa[4], pb[2];
#pragma unroll
  for (int j = 0; j < 4; ++j) {
    int idx = tid + j * 256;
    pa[j] = *(const uint4*)(A + (size_t)(m0 + (idx >> 3)) * 512 + (idx & 7) * 8);
  }
#pragma unroll
  for (int j = 0; j < 2; ++j) {
    int idx = tid + j * 256;
    pb[j] = *(const uint4*)(Bt + (size_t)(n0 + (idx >> 3)) * 512 + (idx & 7) * 8);
  }

  for (int kt = 0; kt < 8; ++kt) {
    __syncthreads();
    // XOR-swizzled LDS store (physical chunk = c16 ^ (row&7)) - T2 pattern
#pragma unroll
    for (int j = 0; j < 4; ++j) {
      int idx = tid + j * 256;
      int sidx = (idx & ~7) | ((idx ^ (idx >> 3)) & 7);
      ((uint4*)As)[sidx] = pa[j];
    }
#pragma unroll
    for (int j = 0; j < 2; ++j) {
      int idx = tid + j * 256;
      int sidx = (idx & ~7) | ((idx ^ (idx >> 3)) & 7);
      ((uint4*)Bs)[sidx] = pb[j];
    }
    if (kt < 7) {
#pragma unroll
      for (int j = 0; j < 4; ++j) {
        int idx = tid + j * 256;
        pa[j] = *(const uint4*)(A + (size_t)(m0 + (idx >> 3)) * 512 +
                                (kt + 1) * 64 + (idx & 7) * 8);
      }
#pragma unroll
      for (int j = 0; j < 2; ++j) {
        int idx = tid + j * 256;
        pb[j] = *(const uint4*)(Bt + (size_t)(n0 + (idx >> 3)) * 512 +
                                (kt + 1) * 64 + (idx & 7) * 8);
      }
    }
    __syncthreads();

#pragma unroll
    for (int kc = 0; kc < 2; ++kc) {
      bf16x8 af[4], bfv[2];
#pragma unroll
      for (int mi = 0; mi < 4; ++mi) {
        int r = wm * 64 + mi * 16 + lr;
        af[mi] = ld_bf16x8(&As[r * 64 + (((kc * 4 + lg) ^ (lr & 7)) << 3)]);
      }
#pragma unroll
      for (int ni = 0; ni < 2; ++ni) {
        int r = wn * 32 + ni * 16 + lr;
        bfv[ni] = ld_bf16x8(&Bs[r * 64 + (((kc * 4 + lg) ^ (lr & 7)) << 3)]);
      }
#pragma unroll
      for (int mi = 0; mi < 4; ++mi)
#pragma unroll
        for (int ni = 0; ni < 2; ++ni)
          acc[mi][ni] = mfma32(af[mi], bfv[ni], acc[mi][ni]);
    }
  }

  // epilogue: D-frag mapping col = lane&15 (n), row = (lane>>4)*4+i (m)
#pragma unroll
  for (int mi = 0; mi < 4; ++mi) {
#pragma unroll
    for (int ni = 0; ni < 2; ++ni) {
      const int mbase = m0 + wm * 64 + mi * 16 + lg * 4;
      const int n = n0 + wn * 32 + ni * 16 + lr;
      const float bsv = bias[n];
      if (mode == 0) {
        u16* o = (u16*)outp;
#pragma unroll
        for (int i = 0; i < 4; ++i)
          o[(size_t)(mbase + i) * 512 + n] = f2b(acc[mi][ni][i] + bsv);
      } else if (mode == 1) {
        // Vt[((b*8+h)*64+d)][t],  b=m>>11, t=m&2047, h=n>>6, d=n&63
        u16* o = (u16*)outp;
        const int bb = mbase >> 11, t = mbase & 2047;
        const size_t rowb = ((size_t)(bb * 8 + (n >> 6)) * 64 + (n & 63)) * 2048;
        *(u32*)(o + rowb + t)     = pack2(acc[mi][ni][0] + bsv, acc[mi][ni][1] + bsv);
        *(u32*)(o + rowb + t + 2) = pack2(acc[mi][ni][2] + bsv, acc[mi][ni][3] + bsv);
      } else {
        float* o = (float*)outp;
#pragma unroll
        for (int i = 0; i < 4; ++i)
          o[(size_t)(mbase + i) * 512 + n] = acc[mi][ni][i] + bsv;
      }
    }
  }
}

// ------------- attention: flash-style, 1 wave = 16 q rows, KVBLK=64 --------
// Q,K: [B*T][512] bf16 ; Vt: [B*H*64][2048] bf16 ; y: [B*T][512] bf16
__global__ __launch_bounds__(256) void k_attn(
    const u16* __restrict__ Q, const u16* __restrict__ K,
    const u16* __restrict__ Vt, const int* __restrict__ mask,
    u16* __restrict__ y) {
  const int b = blockIdx.z, h = blockIdx.y, qt = blockIdx.x;
  const int tid = threadIdx.x, lane = tid & 63, w = tid >> 6;
  const int lr = lane & 15, lg = lane >> 4;
  const int q0 = qt * 64 + w * 16;
  const int fq = (q0 + lr) >> 2;  // query frame (per lane)

  __shared__ int mlds[2048];
#pragma unroll
  for (int j = 0; j < 8; ++j)
    mlds[tid + j * 256] = mask[b * 2048 + tid + j * 256];
  __syncthreads();

  const size_t brow = (size_t)b * 2048;
  const u16* qp = Q + (brow + q0 + lr) * 512 + h * 64 + lg * 8;
  const bf16x8 qf0 = ld_bf16x8(qp);
  const bf16x8 qf1 = ld_bf16x8(qp + 32);
  const u16* kbase = K + brow * 512 + h * 64 + lg * 8;
  const u16* vbase = Vt + (((size_t)b * 8 + h) * 64 + lr) * 2048 + lg * 4;

  const f32x4 fz = {0.f, 0.f, 0.f, 0.f};
  f32x4 yacc[4];
#pragma unroll
  for (int dt = 0; dt < 4; ++dt) yacc[dt] = fz;
  float mrun = -__builtin_inff(), lrun = 0.f;

  const int nchunk = qt + 1;  // 64-key chunks; last one contains the diagonal
  for (int c = 0; c < nchunk; ++c) {
    const int c0 = c << 6;

    // ---- QK^T for 4 sub-tiles (8 MFMAs, 4 independent chains of 2) ----
    f32x4 s[4];
#pragma unroll
    for (int kt = 0; kt < 4; ++kt) {
      const u16* kp = kbase + (size_t)(c0 + kt * 16 + lr) * 512;
      s[kt] = mfma32(ld_bf16x8(kp), qf0, fz);
    }
#pragma unroll
    for (int kt = 0; kt < 4; ++kt) {
      const u16* kp = kbase + (size_t)(c0 + kt * 16 + lr) * 512;
      s[kt] = mfma32(ld_bf16x8(kp + 32), qf1, s[kt]);
    }

    // ---- mask + scale, 16 scores per lane ----
    float sv[4][4];
    float tm = -__builtin_inff();
#pragma unroll
    for (int kt = 0; kt < 4; ++kt) {
      const int k0 = c0 + kt * 16;
      const bool kill = ((k0 >> 2) + lg) > fq;  // frame causal (i-uniform)
      const int4 mv = *(const int4*)&mlds[k0 + lg * 4];
#pragma unroll
      for (int i = 0; i < 4; ++i) {
        const int mvi = (i == 0) ? mv.x : (i == 1) ? mv.y : (i == 2) ? mv.z : mv.w;
        float v = s[kt][i] * 0.125f;
        if (kill || mvi == 0) v = -__builtin_inff();
        sv[kt][i] = v;
        tm = fmaxf(tm, v);
      }
    }
    tm = fmaxf(tm, __shfl_xor(tm, 16));
    tm = fmaxf(tm, __shfl_xor(tm, 32));

    const float mnew = fmaxf(mrun, tm);
    const float msafe = (mnew == -__builtin_inff()) ? 0.f : mnew;
    const float alpha =
        (mrun == -__builtin_inff()) ? 0.f : __expf(mrun - msafe);

    float psum = 0.f;
    s16x4 pf[4];
#pragma unroll
    for (int kt = 0; kt < 4; ++kt) {
#pragma unroll
      for (int i = 0; i < 4; ++i) {
        const float p = __expf(sv[kt][i] - msafe);
        psum += p;
        pf[kt][i] = (short)f2b(p);
      }
    }
    psum += __shfl_xor(psum, 16);
    psum += __shfl_xor(psum, 32);
    lrun = lrun * alpha + psum;
    mrun = mnew;

    // ---- PV: 16 MFMAs, 4 independent chains (one per dt) ----
#pragma unroll
    for (int dt = 0; dt < 4; ++dt) {
#pragma unroll
      for (int i = 0; i < 4; ++i) yacc[dt][i] *= alpha;
#pragma unroll
      for (int kt = 0; kt < 4; ++kt) {
        const uint2 vv =
            *(const uint2*)(vbase + (size_t)dt * 16 * 2048 + c0 + kt * 16);
        yacc[dt] = mfma16(__builtin_bit_cast(s16x4, vv), pf[kt], yacc[dt]);
      }
    }
  }

  const float inv = 1.f / lrun;
#pragma unroll
  for (int dt = 0; dt < 4; ++dt) {
    u32* p2 = (u32*)(y + (brow + q0 + lr) * 512 + h * 64 + dt * 16 + lg * 4);
    p2[0] = pack2(yacc[dt][0] * inv, yacc[dt][1] * inv);
    p2[1] = pack2(yacc[dt][2] * inv, yacc[dt][3] * inv);
  }
}

extern "C" void kernel_launch(void* const* d_in, const int* in_sizes, int n_in,
                              void* d_out, int out_size, void* d_ws,
                              size_t ws_size, hipStream_t stream) {
  const float* x  = (const float*)d_in[0];
  const int* mask = (const int*)d_in[1];
  const float* Wq = (const float*)d_in[2];
  const float* bq = (const float*)d_in[3];
  const float* Wk = (const float*)d_in[4];
  const float* bk = (const float*)d_in[5];
  const float* Wv = (const float*)d_in[6];
  const float* bv = (const float*)d_in[7];
  const float* Wp = (const float*)d_in[8];
  const float* bp = (const float*)d_in[9];

  char* ws = (char*)d_ws;
  u16* xb  = (u16*)(ws);
  u16* wqt = (u16*)(ws + (4u << 20));
  u16* wkt = (u16*)(ws + (4u << 20) + 524288u);
  u16* wvt = (u16*)(ws + (5u << 20));
  u16* wpt = (u16*)(ws + (5u << 20) + 524288u);
  u16* Qb  = (u16*)(ws + (6u << 20));
  u16* Kb  = (u16*)(ws + (10u << 20));
  u16* Vtb = (u16*)(ws + (14u << 20));
  u16* yb  = (u16*)(ws + (18u << 20));

  k_cvt_x<<<dim3(1024), dim3(256), 0, stream>>>(x, xb);
  k_cvt_w<<<dim3(16, 16, 4), dim3(32, 8), 0, stream>>>(Wq, Wk, Wv, Wp, wqt, wkt,
                                                       wvt, wpt);
  k_gemm<<<dim3(8, 32, 3), dim3(256), 0, stream>>>(
      xb, wqt, wkt, wvt, bq, bk, bv, (void*)Qb, (void*)Kb, (void*)Vtb, 0, 0, 1);
  k_attn<<<dim3(32, 8, 2), dim3(256), 0, stream>>>(Qb, Kb, Vtb, mask, yb);
  k_gemm<<<dim3(8, 32, 1), dim3(256), 0, stream>>>(
      yb, wpt, wpt, wpt, bp, bp, bp, d_out, d_out, d_out, 2, 2, 2);
}

// Round 4
// 251.081 us; speedup vs baseline: 1.3143x; 1.3143x over previous
//
#include <hip/hip_runtime.h>

// Requires ws_size >= 22 MiB.
// ws layout (bytes):
//   xb   @ 0        : [4096][512] bf16   (x converted)            4 MiB
//   wqt  @ 4M       : [512][512]  bf16   (Wq^T)                 0.5 MiB
//   wkt  @ 4M+512K  : Wk^T                                      0.5 MiB
//   wvt  @ 5M       : Wv^T                                      0.5 MiB
//   wpt  @ 5M+512K  : Wp^T                                      0.5 MiB
//   Qb   @ 6M       : [B*T][512] bf16                             4 MiB
//   Kb   @ 10M      : [B*T][512] bf16                             4 MiB
//   Vtb  @ 14M      : [B*H*64][2048] bf16  (V transposed)         4 MiB
//   yb   @ 18M      : [B*T][512] bf16  (attention output)         4 MiB

typedef unsigned short u16;
typedef unsigned int   u32;
typedef __bf16 bf16x8 __attribute__((ext_vector_type(8)));
typedef float  f32x4  __attribute__((ext_vector_type(4)));
typedef short  s16x4  __attribute__((ext_vector_type(4)));

static __device__ __forceinline__ u16 f2b(float f) {
  __bf16 h = (__bf16)f;
  return __builtin_bit_cast(u16, h);
}
static __device__ __forceinline__ u32 pack2(float a, float b) {
  return (u32)f2b(a) | ((u32)f2b(b) << 16);
}
static __device__ __forceinline__ bf16x8 ld_bf16x8(const u16* p) {
  uint4 u = *(const uint4*)p;
  return __builtin_bit_cast(bf16x8, u);
}
static __device__ __forceinline__ bf16x8 u4_to_bf(uint4 u) {
  return __builtin_bit_cast(bf16x8, u);
}
static __device__ __forceinline__ f32x4 mfma32(bf16x8 a, bf16x8 b, f32x4 c) {
  return __builtin_amdgcn_mfma_f32_16x16x32_bf16(a, b, c, 0, 0, 0);
}
static __device__ __forceinline__ f32x4 mfma16(s16x4 a, s16x4 b, f32x4 c) {
  return __builtin_amdgcn_mfma_f32_16x16x16bf16_1k(a, b, c, 0, 0, 0);
}

// ---------------- convert x: f32 -> bf16, [4096][512] ----------------
__global__ __launch_bounds__(256) void k_cvt_x(const float* __restrict__ x,
                                               u16* __restrict__ xb) {
  int i = blockIdx.x * 256 + threadIdx.x;   // each thread: 8 elements
  const float4* s = (const float4*)x;
  float4 a = s[2 * i], b = s[2 * i + 1];
  uint4 o;
  o.x = pack2(a.x, a.y);
  o.y = pack2(a.z, a.w);
  o.z = pack2(b.x, b.y);
  o.w = pack2(b.z, b.w);
  ((uint4*)xb)[i] = o;
}

// ------------- convert + transpose weights: Wt[n][k] = W[k][n] -------------
__global__ __launch_bounds__(256) void k_cvt_w(
    const float* __restrict__ Wq, const float* __restrict__ Wk,
    const float* __restrict__ Wv, const float* __restrict__ Wp,
    u16* __restrict__ oq, u16* __restrict__ ok,
    u16* __restrict__ ov, u16* __restrict__ op) {
  const int z = blockIdx.z;
  const float* src = (z == 0) ? Wq : (z == 1) ? Wk : (z == 2) ? Wv : Wp;
  u16* dst = (z == 0) ? oq : (z == 1) ? ok : (z == 2) ? ov : op;
  __shared__ float t[32][33];
  const int tx = threadIdx.x, ty = threadIdx.y;       // 32 x 8
  const int n0 = blockIdx.x * 32, k0 = blockIdx.y * 32;
#pragma unroll
  for (int i = 0; i < 4; ++i)
    t[ty + i * 8][tx] = src[(size_t)(k0 + ty + i * 8) * 512 + n0 + tx];
  __syncthreads();
#pragma unroll
  for (int i = 0; i < 4; ++i)
    dst[(size_t)(n0 + ty + i * 8) * 512 + k0 + tx] = f2b(t[tx][ty + i * 8]);
}

// ---------------- GEMM: C[m][n] = sum_k A[m][k] * Bt[n][k] + bias[n] -------
// M=4096, N=512, K=512. Tile 128x64, BK=64, 4 waves (2x2), 16x16x32 MFMA.
// mode 0: out bf16 [M][N]        (Q, K)
// mode 1: out bf16 Vt[B,H,D,T]   (V transposed)
// mode 2: out f32  [M][N]        (final projection)
__global__ __launch_bounds__(256) void k_gemm(
    const u16* __restrict__ A,
    const u16* __restrict__ Bt_0, const u16* __restrict__ Bt_1,
    const u16* __restrict__ Bt_2,
    const float* __restrict__ bias_0, const float* __restrict__ bias_1,
    const float* __restrict__ bias_2,
    void* out_0, void* out_1, void* out_2,
    int mode_0, int mode_1, int mode_2) {
  const int z = blockIdx.z;
  const u16* Bt = (z == 0) ? Bt_0 : (z == 1) ? Bt_1 : Bt_2;
  const float* bias = (z == 0) ? bias_0 : (z == 1) ? bias_1 : bias_2;
  void* outp = (z == 0) ? out_0 : (z == 1) ? out_1 : out_2;
  const int mode = (z == 0) ? mode_0 : (z == 1) ? mode_1 : mode_2;

  const int tid = threadIdx.x, lane = tid & 63, w = tid >> 6;
  const int wm = w >> 1, wn = w & 1;
  const int lr = lane & 15, lg = lane >> 4;
  const int m0 = blockIdx.y * 128, n0 = blockIdx.x * 64;

  __shared__ __align__(16) u16 As[128 * 64];
  __shared__ __align__(16) u16 Bs[64 * 64];

  f32x4 acc[4][2];
  const f32x4 fz = {0.f, 0.f, 0.f, 0.f};
#pragma unroll
  for (int mi = 0; mi < 4; ++mi)
#pragma unroll
    for (int ni = 0; ni < 2; ++ni) acc[mi][ni] = fz;

  uint4 pa[4], pb[2];
#pragma unroll
  for (int j = 0; j < 4; ++j) {
    int idx = tid + j * 256;
    pa[j] = *(const uint4*)(A + (size_t)(m0 + (idx >> 3)) * 512 + (idx & 7) * 8);
  }
#pragma unroll
  for (int j = 0; j < 2; ++j) {
    int idx = tid + j * 256;
    pb[j] = *(const uint4*)(Bt + (size_t)(n0 + (idx >> 3)) * 512 + (idx & 7) * 8);
  }

  for (int kt = 0; kt < 8; ++kt) {
    __syncthreads();
    // XOR-swizzled LDS store (physical chunk = c16 ^ (row&7)) - T2 pattern
#pragma unroll
    for (int j = 0; j < 4; ++j) {
      int idx = tid + j * 256;
      int sidx = (idx & ~7) | ((idx ^ (idx >> 3)) & 7);
      ((uint4*)As)[sidx] = pa[j];
    }
#pragma unroll
    for (int j = 0; j < 2; ++j) {
      int idx = tid + j * 256;
      int sidx = (idx & ~7) | ((idx ^ (idx >> 3)) & 7);
      ((uint4*)Bs)[sidx] = pb[j];
    }
    if (kt < 7) {
#pragma unroll
      for (int j = 0; j < 4; ++j) {
        int idx = tid + j * 256;
        pa[j] = *(const uint4*)(A + (size_t)(m0 + (idx >> 3)) * 512 +
                                (kt + 1) * 64 + (idx & 7) * 8);
      }
#pragma unroll
      for (int j = 0; j < 2; ++j) {
        int idx = tid + j * 256;
        pb[j] = *(const uint4*)(Bt + (size_t)(n0 + (idx >> 3)) * 512 +
                                (kt + 1) * 64 + (idx & 7) * 8);
      }
    }
    __syncthreads();

#pragma unroll
    for (int kc = 0; kc < 2; ++kc) {
      bf16x8 af[4], bfv[2];
#pragma unroll
      for (int mi = 0; mi < 4; ++mi) {
        int r = wm * 64 + mi * 16 + lr;
        af[mi] = ld_bf16x8(&As[r * 64 + (((kc * 4 + lg) ^ (lr & 7)) << 3)]);
      }
#pragma unroll
      for (int ni = 0; ni < 2; ++ni) {
        int r = wn * 32 + ni * 16 + lr;
        bfv[ni] = ld_bf16x8(&Bs[r * 64 + (((kc * 4 + lg) ^ (lr & 7)) << 3)]);
      }
#pragma unroll
      for (int mi = 0; mi < 4; ++mi)
#pragma unroll
        for (int ni = 0; ni < 2; ++ni)
          acc[mi][ni] = mfma32(af[mi], bfv[ni], acc[mi][ni]);
    }
  }

  // epilogue: D-frag mapping col = lane&15 (n), row = (lane>>4)*4+i (m)
#pragma unroll
  for (int mi = 0; mi < 4; ++mi) {
#pragma unroll
    for (int ni = 0; ni < 2; ++ni) {
      const int mbase = m0 + wm * 64 + mi * 16 + lg * 4;
      const int n = n0 + wn * 32 + ni * 16 + lr;
      const float bsv = bias[n];
      if (mode == 0) {
        u16* o = (u16*)outp;
#pragma unroll
        for (int i = 0; i < 4; ++i)
          o[(size_t)(mbase + i) * 512 + n] = f2b(acc[mi][ni][i] + bsv);
      } else if (mode == 1) {
        // Vt[((b*8+h)*64+d)][t],  b=m>>11, t=m&2047, h=n>>6, d=n&63
        u16* o = (u16*)outp;
        const int bb = mbase >> 11, t = mbase & 2047;
        const size_t rowb = ((size_t)(bb * 8 + (n >> 6)) * 64 + (n & 63)) * 2048;
        *(u32*)(o + rowb + t)     = pack2(acc[mi][ni][0] + bsv, acc[mi][ni][1] + bsv);
        *(u32*)(o + rowb + t + 2) = pack2(acc[mi][ni][2] + bsv, acc[mi][ni][3] + bsv);
      } else {
        float* o = (float*)outp;
#pragma unroll
        for (int i = 0; i < 4; ++i)
          o[(size_t)(mbase + i) * 512 + n] = acc[mi][ni][i] + bsv;
      }
    }
  }
}

// ---- attention: flash-style, reg double-buffered K/V, paired q-tiles ------
// Grid (16, 8, 2), 512 threads (8 waves). Waves 0-3 -> q-tile p (light),
// waves 4-7 -> q-tile 31-p (heavy). Wave w and w+4 share a SIMD -> each SIMD
// has one light + one heavy wave = uniform 33 chunk-equivalents.
// Q,K: [B*T][512] bf16 ; Vt: [B*H*64][2048] bf16 ; y: [B*T][512] bf16
struct KVBuf {
  uint4 k0[4], k1[4];   // K rows: [16 rows x 16B] x 4 sub-tiles, two halves
  uint2 v[4][4];        // V: [dt][kt] 8B each
};

__global__ __launch_bounds__(512, 2) void k_attn(
    const u16* __restrict__ Q, const u16* __restrict__ K,
    const u16* __restrict__ Vt, const int* __restrict__ mask,
    u16* __restrict__ y) {
  const int b = blockIdx.z, h = blockIdx.y, p = blockIdx.x;
  const int tid = threadIdx.x, lane = tid & 63, w = tid >> 6;
  const int lr = lane & 15, lg = lane >> 4;
  const int qt = (w < 4) ? p : (31 - p);
  const int q0 = qt * 64 + (w & 3) * 16;
  const int fq = (q0 + lr) >> 2;  // query frame (per lane)

  __shared__ int mlds[2048];
#pragma unroll
  for (int j = 0; j < 4; ++j)
    mlds[tid + j * 512] = mask[b * 2048 + tid + j * 512];
  __syncthreads();   // the only barrier; per-wave loops differ in trip count

  const size_t brow = (size_t)b * 2048;
  const u16* qp = Q + (brow + q0 + lr) * 512 + h * 64 + lg * 8;
  const bf16x8 qf0 = ld_bf16x8(qp);
  const bf16x8 qf1 = ld_bf16x8(qp + 32);
  const u16* kbase = K + brow * 512 + h * 64 + lg * 8;
  const u16* vbase = Vt + (((size_t)b * 8 + h) * 64 + lr) * 2048 + lg * 4;

  const f32x4 fz = {0.f, 0.f, 0.f, 0.f};
  f32x4 yacc[4];
#pragma unroll
  for (int dt = 0; dt < 4; ++dt) yacc[dt] = fz;
  float mrun = -__builtin_inff(), lrun = 0.f;

  auto load_kv = [&](KVBuf& buf, int c0) {
#pragma unroll
    for (int kt = 0; kt < 4; ++kt) {
      const u16* kp = kbase + (size_t)(c0 + kt * 16 + lr) * 512;
      buf.k0[kt] = *(const uint4*)kp;
      buf.k1[kt] = *(const uint4*)(kp + 32);
    }
#pragma unroll
    for (int dt = 0; dt < 4; ++dt)
#pragma unroll
      for (int kt = 0; kt < 4; ++kt)
        buf.v[dt][kt] =
            *(const uint2*)(vbase + (size_t)dt * 32768 + c0 + kt * 16);
  };

  auto compute = [&](const KVBuf& buf, int c0) {
    // ---- QK^T: 8 MFMAs, 4 independent chains of 2 ----
    f32x4 s[4];
#pragma unroll
    for (int kt = 0; kt < 4; ++kt) s[kt] = mfma32(u4_to_bf(buf.k0[kt]), qf0, fz);
#pragma unroll
    for (int kt = 0; kt < 4; ++kt)
      s[kt] = mfma32(u4_to_bf(buf.k1[kt]), qf1, s[kt]);

    // ---- mask + scale, 16 scores per lane ----
    float sv[4][4];
    float tm = -__builtin_inff();
#pragma unroll
    for (int kt = 0; kt < 4; ++kt) {
      const int k0 = c0 + kt * 16;
      const bool kill = ((k0 >> 2) + lg) > fq;  // frame causal (i-uniform)
      const int4 mv = *(const int4*)&mlds[k0 + lg * 4];
#pragma unroll
      for (int i = 0; i < 4; ++i) {
        const int mvi = (i == 0) ? mv.x : (i == 1) ? mv.y : (i == 2) ? mv.z : mv.w;
        float v = s[kt][i] * 0.125f;
        if (kill || mvi == 0) v = -__builtin_inff();
        sv[kt][i] = v;
        tm = fmaxf(tm, v);
      }
    }
    tm = fmaxf(tm, __shfl_xor(tm, 16));
    tm = fmaxf(tm, __shfl_xor(tm, 32));

    const float mnew = fmaxf(mrun, tm);
    const float msafe = (mnew == -__builtin_inff()) ? 0.f : mnew;
    const float alpha =
        (mrun == -__builtin_inff()) ? 0.f : __expf(mrun - msafe);

    float psum = 0.f;
    s16x4 pf[4];
#pragma unroll
    for (int kt = 0; kt < 4; ++kt) {
#pragma unroll
      for (int i = 0; i < 4; ++i) {
        const float pv = __expf(sv[kt][i] - msafe);
        psum += pv;
        pf[kt][i] = (short)f2b(pv);
      }
    }
    psum += __shfl_xor(psum, 16);
    psum += __shfl_xor(psum, 32);
    lrun = lrun * alpha + psum;
    mrun = mnew;

    // ---- PV: 16 MFMAs, 4 independent chains (one per dt) ----
#pragma unroll
    for (int dt = 0; dt < 4; ++dt) {
#pragma unroll
      for (int i = 0; i < 4; ++i) yacc[dt][i] *= alpha;
#pragma unroll
      for (int kt = 0; kt < 4; ++kt)
        yacc[dt] =
            mfma16(__builtin_bit_cast(s16x4, buf.v[dt][kt]), pf[kt], yacc[dt]);
    }
  };

  const int nchunk = qt + 1;  // 64-key chunks; last contains the diagonal
  KVBuf A, B;
  load_kv(A, 0);
  int c = 0;
  for (; c + 2 <= nchunk; c += 2) {
    load_kv(B, (c + 1) << 6);        // prefetch c+1 while computing c
    compute(A, c << 6);
    if (c + 2 < nchunk) load_kv(A, (c + 2) << 6);  // prefetch c+2
    compute(B, (c + 1) << 6);
  }
  if (c < nchunk) compute(A, c << 6);  // odd tail

  const float inv = 1.f / lrun;
#pragma unroll
  for (int dt = 0; dt < 4; ++dt) {
    u32* p2 = (u32*)(y + (brow + q0 + lr) * 512 + h * 64 + dt * 16 + lg * 4);
    p2[0] = pack2(yacc[dt][0] * inv, yacc[dt][1] * inv);
    p2[1] = pack2(yacc[dt][2] * inv, yacc[dt][3] * inv);
  }
}

extern "C" void kernel_launch(void* const* d_in, const int* in_sizes, int n_in,
                              void* d_out, int out_size, void* d_ws,
                              size_t ws_size, hipStream_t stream) {
  const float* x  = (const float*)d_in[0];
  const int* mask = (const int*)d_in[1];
  const float* Wq = (const float*)d_in[2];
  const float* bq = (const float*)d_in[3];
  const float* Wk = (const float*)d_in[4];
  const float* bk = (const float*)d_in[5];
  const float* Wv = (const float*)d_in[6];
  const float* bv = (const float*)d_in[7];
  const float* Wp = (const float*)d_in[8];
  const float* bp = (const float*)d_in[9];

  char* ws = (char*)d_ws;
  u16* xb  = (u16*)(ws);
  u16* wqt = (u16*)(ws + (4u << 20));
  u16* wkt = (u16*)(ws + (4u << 20) + 524288u);
  u16* wvt = (u16*)(ws + (5u << 20));
  u16* wpt = (u16*)(ws + (5u << 20) + 524288u);
  u16* Qb  = (u16*)(ws + (6u << 20));
  u16* Kb  = (u16*)(ws + (10u << 20));
  u16* Vtb = (u16*)(ws + (14u << 20));
  u16* yb  = (u16*)(ws + (18u << 20));

  k_cvt_x<<<dim3(1024), dim3(256), 0, stream>>>(x, xb);
  k_cvt_w<<<dim3(16, 16, 4), dim3(32, 8), 0, stream>>>(Wq, Wk, Wv, Wp, wqt, wkt,
                                                       wvt, wpt);
  k_gemm<<<dim3(8, 32, 3), dim3(256), 0, stream>>>(
      xb, wqt, wkt, wvt, bq, bk, bv, (void*)Qb, (void*)Kb, (void*)Vtb, 0, 0, 1);
  k_attn<<<dim3(16, 8, 2), dim3(512), 0, stream>>>(Qb, Kb, Vtb, mask, yb);
  k_gemm<<<dim3(8, 32, 1), dim3(256), 0, stream>>>(
      yb, wpt, wpt, wpt, bp, bp, bp, d_out, d_out, d_out, 2, 2, 2);
}

// Round 6
// 158.669 us; speedup vs baseline: 2.0798x; 1.5824x over previous
//
#include <hip/hip_runtime.h>

// Requires ws_size >= 22 MiB. ws layout (bytes):
//   xb   @ 0        : [4096][512] bf16   (x converted)            4 MiB
//   wqt  @ 4M       : [512][512]  bf16   (Wq^T)                 0.5 MiB
//   wkt  @ 4M+512K  : Wk^T                                      0.5 MiB
//   wvt  @ 5M       : Wv^T                                      0.5 MiB
//   wpt  @ 5M+512K  : Wp^T                                      0.5 MiB
//   Qb   @ 6M       : [B*T][512] bf16                             4 MiB
//   Kb   @ 10M      : [B*T][512] bf16                             4 MiB
//   Vtb  @ 14M      : [B*H*64][2048] bf16  (V transposed)         4 MiB
//   yb   @ 18M      : [B*T][512] bf16  (attention output)         4 MiB

typedef unsigned short u16;
typedef unsigned int   u32;
typedef __bf16 bf16x8 __attribute__((ext_vector_type(8)));
typedef float  f32x4  __attribute__((ext_vector_type(4)));
typedef short  s16x4  __attribute__((ext_vector_type(4)));

static __device__ __forceinline__ u16 f2b(float f) {
  __bf16 h = (__bf16)f;
  return __builtin_bit_cast(u16, h);
}
static __device__ __forceinline__ u32 pack2(float a, float b) {
  return (u32)f2b(a) | ((u32)f2b(b) << 16);
}
static __device__ __forceinline__ bf16x8 ld_bf16x8(const u16* p) {
  uint4 u = *(const uint4*)p;
  return __builtin_bit_cast(bf16x8, u);
}
static __device__ __forceinline__ f32x4 mfma32(bf16x8 a, bf16x8 b, f32x4 c) {
  return __builtin_amdgcn_mfma_f32_16x16x32_bf16(a, b, c, 0, 0, 0);
}
static __device__ __forceinline__ f32x4 mfma16(s16x4 a, s16x4 b, f32x4 c) {
  return __builtin_amdgcn_mfma_f32_16x16x16bf16_1k(a, b, c, 0, 0, 0);
}
// async global->LDS, 16 B per lane; lds dest = wave-uniform base + lane*16
static __device__ __forceinline__ void gload16(const u16* g, u16* l) {
  __builtin_amdgcn_global_load_lds(
      (const __attribute__((address_space(1))) void*)g,
      (__attribute__((address_space(3))) void*)l, 16, 0, 0);
}

// ---------------- convert x: f32 -> bf16, [4096][512] ----------------
__global__ __launch_bounds__(256) void k_cvt_x(const float* __restrict__ x,
                                               u16* __restrict__ xb) {
  int i = blockIdx.x * 256 + threadIdx.x;   // each thread: 8 elements
  const float4* s = (const float4*)x;
  float4 a = s[2 * i], b = s[2 * i + 1];
  uint4 o;
  o.x = pack2(a.x, a.y);
  o.y = pack2(a.z, a.w);
  o.z = pack2(b.x, b.y);
  o.w = pack2(b.z, b.w);
  ((uint4*)xb)[i] = o;
}

// ------------- convert + transpose weights: Wt[n][k] = W[k][n] -------------
__global__ __launch_bounds__(256) void k_cvt_w(
    const float* __restrict__ Wq, const float* __restrict__ Wk,
    const float* __restrict__ Wv, const float* __restrict__ Wp,
    u16* __restrict__ oq, u16* __restrict__ ok,
    u16* __restrict__ ov, u16* __restrict__ op) {
  const int z = blockIdx.z;
  const float* src = (z == 0) ? Wq : (z == 1) ? Wk : (z == 2) ? Wv : Wp;
  u16* dst = (z == 0) ? oq : (z == 1) ? ok : (z == 2) ? ov : op;
  __shared__ float t[32][33];
  const int tx = threadIdx.x, ty = threadIdx.y;       // 32 x 8
  const int n0 = blockIdx.x * 32, k0 = blockIdx.y * 32;
#pragma unroll
  for (int i = 0; i < 4; ++i)
    t[ty + i * 8][tx] = src[(size_t)(k0 + ty + i * 8) * 512 + n0 + tx];
  __syncthreads();
#pragma unroll
  for (int i = 0; i < 4; ++i)
    dst[(size_t)(n0 + ty + i * 8) * 512 + k0 + tx] = f2b(t[tx][ty + i * 8]);
}

// ---------------- GEMM: C[m][n] = sum_k A[m][k] * Bt[n][k] + bias[n] -------
// BM x 128 tile, BK=64, 512 thr (8 waves, 2x4), global_load_lds dbuf staging.
// LDS logical layout [row][64] with XOR chunk swizzle (phys chunk = c ^ (row&7)),
// realized by pre-swizzling the per-lane GLOBAL source (linear LDS dest).
// mode 0: out bf16 [M][N] ; mode 1: out bf16 Vt[B,H,D,T] ; mode 2: out f32.
template <int BM>
__global__ __launch_bounds__(512) void k_gemm(
    const u16* __restrict__ A,
    const u16* __restrict__ Bt_0, const u16* __restrict__ Bt_1,
    const u16* __restrict__ Bt_2,
    const float* __restrict__ bias_0, const float* __restrict__ bias_1,
    const float* __restrict__ bias_2,
    void* out_0, void* out_1, void* out_2,
    int mode_0, int mode_1, int mode_2) {
  const int z = blockIdx.z;
  const u16* Bt = (z == 0) ? Bt_0 : (z == 1) ? Bt_1 : Bt_2;
  const float* bias = (z == 0) ? bias_0 : (z == 1) ? bias_1 : bias_2;
  void* outp = (z == 0) ? out_0 : (z == 1) ? out_1 : out_2;
  const int mode = (z == 0) ? mode_0 : (z == 1) ? mode_1 : mode_2;

  constexpr int MI = BM / 32;     // m-frags per wave (wave tile BM/2 x 32)
  const int tid = threadIdx.x, lane = tid & 63, w = tid >> 6;
  const int wm = w >> 2, wn = w & 3;          // 2 x 4 wave grid
  const int lr = lane & 15, lg = lane >> 4;
  const int m0 = blockIdx.y * BM, n0 = blockIdx.x * 128;

  __shared__ __align__(16) u16 As[2][BM * 64];
  __shared__ __align__(16) u16 Bs[2][128 * 64];

  f32x4 acc[MI][2];
  const f32x4 fz = {0.f, 0.f, 0.f, 0.f};
#pragma unroll
  for (int mi = 0; mi < MI; ++mi)
#pragma unroll
    for (int ni = 0; ni < 2; ++ni) acc[mi][ni] = fz;

  // staging: lane covers row r0 + (lane>>3), source chunk pre-swizzled
  const int lro = lane >> 3;
  const int lch = (lane & 7) ^ (lro & 7);

  auto stage = [&](int kk, int buf) {
#pragma unroll
    for (int j = 0; j < BM / 64; ++j) {       // A: BM=128 -> 2, BM=64 -> 1
      const int r0 = w * (BM / 8) + j * 8;
      gload16(A + (size_t)(m0 + r0 + lro) * 512 + kk + lch * 8,
              &As[buf][r0 * 64]);
    }
#pragma unroll
    for (int j = 0; j < 2; ++j) {             // B: 16 rows per wave
      const int r0 = w * 16 + j * 8;
      gload16(Bt + (size_t)(n0 + r0 + lro) * 512 + kk + lch * 8,
              &Bs[buf][r0 * 64]);
    }
  };

  stage(0, 0);
  __syncthreads();
  for (int kt = 0; kt < 8; ++kt) {
    if (kt + 1 < 8) stage((kt + 1) * 64, (kt + 1) & 1);
    const int buf = kt & 1;
#pragma unroll
    for (int kc = 0; kc < 2; ++kc) {
      bf16x8 af[MI], bfv[2];
#pragma unroll
      for (int mi = 0; mi < MI; ++mi) {
        const int r = wm * (BM / 2) + mi * 16 + lr;
        af[mi] = ld_bf16x8(&As[buf][r * 64 + (((kc * 4 + lg) ^ (r & 7)) << 3)]);
      }
#pragma unroll
      for (int ni = 0; ni < 2; ++ni) {
        const int r = wn * 32 + ni * 16 + lr;
        bfv[ni] = ld_bf16x8(&Bs[buf][r * 64 + (((kc * 4 + lg) ^ (r & 7)) << 3)]);
      }
#pragma unroll
      for (int mi = 0; mi < MI; ++mi)
#pragma unroll
        for (int ni = 0; ni < 2; ++ni)
          acc[mi][ni] = mfma32(af[mi], bfv[ni], acc[mi][ni]);
    }
    __syncthreads();
  }

  // epilogue: D-frag mapping col = lane&15 (n), row = (lane>>4)*4+i (m)
#pragma unroll
  for (int mi = 0; mi < MI; ++mi) {
#pragma unroll
    for (int ni = 0; ni < 2; ++ni) {
      const int mbase = m0 + wm * (BM / 2) + mi * 16 + lg * 4;
      const int n = n0 + wn * 32 + ni * 16 + lr;
      const float bsv = bias[n];
      if (mode == 0) {
        u16* o = (u16*)outp;
#pragma unroll
        for (int i = 0; i < 4; ++i)
          o[(size_t)(mbase + i) * 512 + n] = f2b(acc[mi][ni][i] + bsv);
      } else if (mode == 1) {
        // Vt[((b*8+h)*64+d)][t],  b=m>>11, t=m&2047, h=n>>6, d=n&63
        u16* o = (u16*)outp;
        const int bb = mbase >> 11, t = mbase & 2047;
        const size_t rowb = ((size_t)(bb * 8 + (n >> 6)) * 64 + (n & 63)) * 2048;
        *(u32*)(o + rowb + t)     = pack2(acc[mi][ni][0] + bsv, acc[mi][ni][1] + bsv);
        *(u32*)(o + rowb + t + 2) = pack2(acc[mi][ni][2] + bsv, acc[mi][ni][3] + bsv);
      } else {
        float* o = (float*)outp;
#pragma unroll
        for (int i = 0; i < 4; ++i)
          o[(size_t)(mbase + i) * 512 + n] = acc[mi][ni][i] + bsv;
      }
    }
  }
}

// ---- attention: flash-style, LDS-shared async K/V staging -----------------
// Block = 256 thr (4 waves) = one 64-row q-tile; qt = 31 - blockIdx.x (LPT).
// K/V chunk (64 keys) staged to double-buffered LDS via global_load_lds;
// XOR chunk swizzle via pre-swizzled global source; 1 barrier per chunk.
// Q,K: [B*T][512] bf16 ; Vt: [B*H*64][2048] bf16 ; y: [B*T][512] bf16
__global__ __launch_bounds__(256) void k_attn(
    const u16* __restrict__ Q, const u16* __restrict__ K,
    const u16* __restrict__ Vt, const int* __restrict__ mask,
    u16* __restrict__ y) {
  const int b = blockIdx.z, h = blockIdx.y;
  const int qt = 31 - blockIdx.x;   // heavy tiles dispatched first
  const int tid = threadIdx.x, lane = tid & 63, w = tid >> 6;
  const int lr = lane & 15, lg = lane >> 4;
  const int q0 = qt * 64 + w * 16;
  const int fq = (q0 + lr) >> 2;    // query frame (per lane)

  __shared__ __align__(16) u16 Ks[2][64 * 64];
  __shared__ __align__(16) u16 Vs[2][64 * 64];

  const size_t brow = (size_t)b * 2048;
  const u16* qp = Q + (brow + q0 + lr) * 512 + h * 64 + lg * 8;
  const bf16x8 qf0 = ld_bf16x8(qp);
  const bf16x8 qf1 = ld_bf16x8(qp + 32);
  const int* maskp = mask + b * 2048;

  const f32x4 fz = {0.f, 0.f, 0.f, 0.f};
  f32x4 yacc[4];
#pragma unroll
  for (int dt = 0; dt < 4; ++dt) yacc[dt] = fz;
  float mrun = -__builtin_inff(), lrun = 0.f;

  const int lro = lane >> 3;
  const int lch = (lane & 7) ^ (lro & 7);
  const u16* kgbase = K + brow * 512 + h * 64 + lch * 8;
  const u16* vgbase = Vt + ((size_t)(b * 8 + h) * 64) * 2048 + lch * 8;

  auto stage = [&](int c, int buf) {
    const int c0 = c << 6;
#pragma unroll
    for (int j = 0; j < 2; ++j) {   // K rows (tokens): wave w covers 16 rows
      const int r0 = w * 16 + j * 8;
      gload16(kgbase + (size_t)(c0 + r0 + lro) * 512, &Ks[buf][r0 * 64]);
    }
#pragma unroll
    for (int j = 0; j < 2; ++j) {   // V rows (d): wave w covers 16 rows
      const int r0 = w * 16 + j * 8;
      gload16(vgbase + (size_t)(r0 + lro) * 2048 + c0, &Vs[buf][r0 * 64]);
    }
  };

  auto compute = [&](int c, int buf) {
    const int c0 = c << 6;
    // ---- QK^T: 8 MFMAs, 4 independent chains of 2 ----
    f32x4 s[4];
#pragma unroll
    for (int kt = 0; kt < 4; ++kt) {
      const int r = kt * 16 + lr;
      s[kt] = mfma32(ld_bf16x8(&Ks[buf][r * 64 + ((lg ^ (r & 7)) << 3)]), qf0, fz);
    }
#pragma unroll
    for (int kt = 0; kt < 4; ++kt) {
      const int r = kt * 16 + lr;
      s[kt] = mfma32(ld_bf16x8(&Ks[buf][r * 64 + (((lg + 4) ^ (r & 7)) << 3)]),
                     qf1, s[kt]);
    }

    // ---- mask + scale, 16 scores per lane ----
    float sv[4][4];
    float tm = -__builtin_inff();
#pragma unroll
    for (int kt = 0; kt < 4; ++kt) {
      const int k0 = c0 + kt * 16;
      const bool kill = ((k0 >> 2) + lg) > fq;  // frame causal (i-uniform)
      const int4 mv = *(const int4*)&maskp[k0 + lg * 4];
#pragma unroll
      for (int i = 0; i < 4; ++i) {
        const int mvi = (i == 0) ? mv.x : (i == 1) ? mv.y : (i == 2) ? mv.z : mv.w;
        float v = s[kt][i] * 0.125f;
        if (kill || mvi == 0) v = -__builtin_inff();
        sv[kt][i] = v;
        tm = fmaxf(tm, v);
      }
    }
    tm = fmaxf(tm, __shfl_xor(tm, 16));
    tm = fmaxf(tm, __shfl_xor(tm, 32));

    const float mnew = fmaxf(mrun, tm);
    const float msafe = (mnew == -__builtin_inff()) ? 0.f : mnew;
    const float alpha =
        (mrun == -__builtin_inff()) ? 0.f : __expf(mrun - msafe);

    float psum = 0.f;
    s16x4 pf[4];
#pragma unroll
    for (int kt = 0; kt < 4; ++kt) {
#pragma unroll
      for (int i = 0; i < 4; ++i) {
        const float pv = __expf(sv[kt][i] - msafe);
        psum += pv;
        pf[kt][i] = (short)f2b(pv);
      }
    }
    psum += __shfl_xor(psum, 16);
    psum += __shfl_xor(psum, 32);
    lrun = lrun * alpha + psum;
    mrun = mnew;

    // ---- PV: 16 MFMAs, 4 independent chains (one per dt) ----
#pragma unroll
    for (int dt = 0; dt < 4; ++dt) {
#pragma unroll
      for (int i = 0; i < 4; ++i) yacc[dt][i] *= alpha;
#pragma unroll
      for (int kt = 0; kt < 4; ++kt) {
        const int r = dt * 16 + lr;
        const int ch = kt * 2 + (lg >> 1);
        const uint2 vv = *(const uint2*)&Vs[buf][r * 64 +
                                                 ((ch ^ (r & 7)) << 3) +
                                                 ((lg & 1) << 2)];
        yacc[dt] = mfma16(__builtin_bit_cast(s16x4, vv), pf[kt], yacc[dt]);
      }
    }
  };

  const int nchunk = qt + 1;
  stage(0, 0);
  __syncthreads();
  for (int c = 0; c < nchunk; ++c) {
    if (c + 1 < nchunk) stage(c + 1, (c + 1) & 1);
    compute(c, c & 1);
    __syncthreads();   // drains stage(c+1); protects buffer reuse
  }

  const float inv = 1.f / lrun;
#pragma unroll
  for (int dt = 0; dt < 4; ++dt) {
    u32* p2 = (u32*)(y + (brow + q0 + lr) * 512 + h * 64 + dt * 16 + lg * 4);
    p2[0] = pack2(yacc[dt][0] * inv, yacc[dt][1] * inv);
    p2[1] = pack2(yacc[dt][2] * inv, yacc[dt][3] * inv);
  }
}

extern "C" void kernel_launch(void* const* d_in, const int* in_sizes, int n_in,
                              void* d_out, int out_size, void* d_ws,
                              size_t ws_size, hipStream_t stream) {
  const float* x  = (const float*)d_in[0];
  const int* mask = (const int*)d_in[1];
  const float* Wq = (const float*)d_in[2];
  const float* bq = (const float*)d_in[3];
  const float* Wk = (const float*)d_in[4];
  const float* bk = (const float*)d_in[5];
  const float* Wv = (const float*)d_in[6];
  const float* bv = (const float*)d_in[7];
  const float* Wp = (const float*)d_in[8];
  const float* bp = (const float*)d_in[9];

  char* ws = (char*)d_ws;
  u16* xb  = (u16*)(ws);
  u16* wqt = (u16*)(ws + (4u << 20));
  u16* wkt = (u16*)(ws + (4u << 20) + 524288u);
  u16* wvt = (u16*)(ws + (5u << 20));
  u16* wpt = (u16*)(ws + (5u << 20) + 524288u);
  u16* Qb  = (u16*)(ws + (6u << 20));
  u16* Kb  = (u16*)(ws + (10u << 20));
  u16* Vtb = (u16*)(ws + (14u << 20));
  u16* yb  = (u16*)(ws + (18u << 20));

  k_cvt_x<<<dim3(1024), dim3(256), 0, stream>>>(x, xb);
  k_cvt_w<<<dim3(16, 16, 4), dim3(32, 8), 0, stream>>>(Wq, Wk, Wv, Wp, wqt, wkt,
                                                       wvt, wpt);
  k_gemm<128><<<dim3(4, 32, 3), dim3(512), 0, stream>>>(
      xb, wqt, wkt, wvt, bq, bk, bv, (void*)Qb, (void*)Kb, (void*)Vtb, 0, 0, 1);
  k_attn<<<dim3(32, 8, 2), dim3(256), 0, stream>>>(Qb, Kb, Vtb, mask, yb);
  k_gemm<64><<<dim3(4, 64, 1), dim3(512), 0, stream>>>(
      yb, wpt, wpt, wpt, bp, bp, bp, d_out, d_out, d_out, 2, 2, 2);
}